// Round 1
// 221.819 us; speedup vs baseline: 1.0991x; 1.0991x over previous
//
#include <hip/hip_runtime.h>
#include <hip/hip_bf16.h>
#include <hip/hip_fp16.h>
#include <stdint.h>

// ---------------------------------------------------------------------------
// CLIPAttentionPooling. R10: latency attack on the 3 MFMA GEMMs.
// R9 counters: gemm_av MfmaUtil 17%, HBM 11%, occupancy 20%, 4.19M LDS bank
// conflicts -> latency/barrier-bound, not roofline.
// Changes (all three GEMMs):
//   * T3-minimal 2-phase pipeline: double-buffered LDS stage, prefetch next
//     K-step before computing current, raw s_barrier + counted vmcnt (never
//     drain to 0 in the main loop).
//   * T2 chunk swizzle: 64-B LDS rows read as ds_read_b128 were 8-way bank
//     conflicted. global_load_lds writes linearly -> swizzle BOTH sides:
//     source chunk ^= (rsub&3) at stage, read chunk = quad ^ (row&3).
// Dispatches unchanged (4): quantT, gemm_proj_i8, gemm_s_stats, gemm_av.
// ---------------------------------------------------------------------------

using half8   = __attribute__((ext_vector_type(8))) _Float16;
using float4v = __attribute__((ext_vector_type(4))) float;
using int4v   = __attribute__((ext_vector_type(4))) int;

// q/k int16 grid: covers +-6.0, v = QS*(256*hi+lo)
#define QS        (6.0f / 32768.0f)
#define INV_S     (32768.0f / 6.0f)
#define INV_S256  (128.0f / 6.0f)
#define C_HH      (65536.0f * QS * QS)
#define C_X       (256.0f * QS * QS)

// x grid: +-6.0 ; W grid: +-0.25
#define SX        (6.0f / 32768.0f)
#define SW        (0.25f / 32768.0f)
#define P_HH      (65536.0f * SX * SW)
#define P_X       (256.0f * SX * SW)

#define GLOAD_LDS16(gptr, ldsptr)                                              \
  __builtin_amdgcn_global_load_lds(                                            \
      (__attribute__((address_space(1))) void*)(uintptr_t)(gptr),              \
      (__attribute__((address_space(3))) void*)(unsigned)(uintptr_t)(ldsptr),  \
      16, 0, 0)

// Raw barrier with compiler memory fences on both sides: keeps LDS reads from
// floating above the barrier (my counted vmcnt only covers MY stage loads;
// other threads' loads are covered only past the barrier).
__device__ __forceinline__ void barrier_raw() {
  asm volatile("" ::: "memory");
  __builtin_amdgcn_s_barrier();
  asm volatile("" ::: "memory");
}

// ---------------------------------------------------------------------------
// S GEMM + tile softmax stats. Split-i8 16x16x64, 128x128 tile, BK=64.
// R10: double-buffered stage + counted vmcnt(8) + chunk swizzle.
__global__ __launch_bounds__(256, 2) void gemm_s_stats(
    const int8_t* __restrict__ Ahi, const int8_t* __restrict__ Alo,
    const int8_t* __restrict__ Bhi, const int8_t* __restrict__ Blo,
    _Float16* __restrict__ E, float2* __restrict__ stats)
{
  __shared__ __align__(16) int8_t sAh[2][128 * 64];
  __shared__ __align__(16) int8_t sAl[2][128 * 64];
  __shared__ __align__(16) int8_t sBh[2][128 * 64];
  __shared__ __align__(16) int8_t sBl[2][128 * 64];

  const int tid  = threadIdx.x;
  const int wave = tid >> 6;
  const int lane = tid & 63;
  const int quad = lane >> 4;
  const int t16  = lane & 15;
  const int wm   = wave & 1;
  const int wn   = wave >> 1;
  const int row0 = blockIdx.y * 128;
  const int col0 = blockIdx.x * 128;

  const int seg  = lane & 3;
  const int rsub = lane >> 2;
  const int segS = seg ^ (rsub & 3);          // swizzled source chunk
  const int rch  = (quad ^ (t16 & 3)) * 16;   // swizzled read chunk (bytes)

  int4v hh[4][4], cc[4][4];
#pragma unroll
  for (int i = 0; i < 4; ++i)
#pragma unroll
    for (int j = 0; j < 4; ++j) {
      hh[i][j] = (int4v){0, 0, 0, 0};
      cc[i][j] = (int4v){0, 0, 0, 0};
    }

  auto stage_k = [&](int ks, int b) {
    const int k0 = ks * 64;
#pragma unroll
    for (int r = 0; r < 2; ++r) {
      const int trow = r * 64 + wave * 16;
      const size_t goffA = (size_t)(row0 + trow + rsub) * 2048 + k0 + segS * 16;
      const size_t goffB = (size_t)(col0 + trow + rsub) * 2048 + k0 + segS * 16;
      GLOAD_LDS16(Ahi + goffA, &sAh[b][trow * 64]);
      GLOAD_LDS16(Alo + goffA, &sAl[b][trow * 64]);
      GLOAD_LDS16(Bhi + goffB, &sBh[b][trow * 64]);
      GLOAD_LDS16(Blo + goffB, &sBl[b][trow * 64]);
    }
  };

  stage_k(0, 0);
  int buf = 0;
  for (int ks = 0; ks < 16; ++ks) {
    if (ks < 15) {
      stage_k(ks + 1, buf ^ 1);
      asm volatile("s_waitcnt vmcnt(8)" ::: "memory");  // my stage(ks) landed
    } else {
      asm volatile("s_waitcnt vmcnt(0)" ::: "memory");
    }
    barrier_raw();  // everyone's stage(ks) landed

    int4v ah[4], al[4], bh[4], bl[4];
#pragma unroll
    for (int i = 0; i < 4; ++i) {
      const int ao = (wm * 64 + i * 16 + t16) * 64 + rch;
      ah[i] = *(const int4v*)&sAh[buf][ao];
      al[i] = *(const int4v*)&sAl[buf][ao];
    }
#pragma unroll
    for (int j = 0; j < 4; ++j) {
      const int bo = (wn * 64 + j * 16 + t16) * 64 + rch;
      bh[j] = *(const int4v*)&sBh[buf][bo];
      bl[j] = *(const int4v*)&sBl[buf][bo];
    }

#pragma unroll
    for (int i = 0; i < 4; ++i)
#pragma unroll
      for (int j = 0; j < 4; ++j) {
        hh[i][j] = __builtin_amdgcn_mfma_i32_16x16x64_i8(ah[i], bh[j], hh[i][j], 0, 0, 0);
        cc[i][j] = __builtin_amdgcn_mfma_i32_16x16x64_i8(ah[i], bl[j], cc[i][j], 0, 0, 0);
        cc[i][j] = __builtin_amdgcn_mfma_i32_16x16x64_i8(al[i], bh[j], cc[i][j], 0, 0, 0);
      }
    barrier_raw();  // reads of buf done before it is restaged
    buf ^= 1;
  }

  // ---- epilogue: tile-local softmax stats (R8-verified) --------------------
  float* red = (float*)sAh;

  float vv[4][4][4];
  float rmax[4][4];
#pragma unroll
  for (int i = 0; i < 4; ++i)
#pragma unroll
    for (int r = 0; r < 4; ++r) {
      float mx = -3.0e38f;
#pragma unroll
      for (int j = 0; j < 4; ++j) {
        float v = C_HH * (float)hh[i][j][r] + C_X * (float)cc[i][j][r];
        vv[i][j][r] = v;
        mx = fmaxf(mx, v);
      }
      mx = fmaxf(mx, __shfl_xor(mx, 1));
      mx = fmaxf(mx, __shfl_xor(mx, 2));
      mx = fmaxf(mx, __shfl_xor(mx, 4));
      mx = fmaxf(mx, __shfl_xor(mx, 8));
      rmax[i][r] = mx;
    }
  if (t16 == 0) {
#pragma unroll
    for (int i = 0; i < 4; ++i)
#pragma unroll
      for (int r = 0; r < 4; ++r)
        red[wn * 128 + wm * 64 + i * 16 + quad * 4 + r] = rmax[i][r];
  }
  __syncthreads();

  float mrow[4][4];
#pragma unroll
  for (int i = 0; i < 4; ++i)
#pragma unroll
    for (int r = 0; r < 4; ++r) {
      const int row = wm * 64 + i * 16 + quad * 4 + r;
      mrow[i][r] = fmaxf(red[row], red[128 + row]);
    }

  float rsum[4][4];
#pragma unroll
  for (int i = 0; i < 4; ++i)
#pragma unroll
    for (int r = 0; r < 4; ++r) {
      float s = 0.f;
#pragma unroll
      for (int j = 0; j < 4; ++j) {
        float e = __expf(vv[i][j][r] - mrow[i][r]);
        vv[i][j][r] = e;
        s += e;
      }
      s += __shfl_xor(s, 1);
      s += __shfl_xor(s, 2);
      s += __shfl_xor(s, 4);
      s += __shfl_xor(s, 8);
      rsum[i][r] = s;
    }
  if (t16 == 0) {
#pragma unroll
    for (int i = 0; i < 4; ++i)
#pragma unroll
      for (int r = 0; r < 4; ++r)
        red[256 + wn * 128 + wm * 64 + i * 16 + quad * 4 + r] = rsum[i][r];
  }
  __syncthreads();

#pragma unroll
  for (int i = 0; i < 4; ++i) {
#pragma unroll
    for (int j = 0; j < 4; ++j) {
#pragma unroll
      for (int r = 0; r < 4; ++r) {
        const int crow = row0 + wm * 64 + i * 16 + quad * 4 + r;
        const int ccol = col0 + wn * 64 + j * 16 + t16;
        E[(size_t)crow * 4096 + ccol] = (_Float16)vv[i][j][r];
      }
    }
  }
  if (wn == 0 && t16 == 0) {
#pragma unroll
    for (int i = 0; i < 4; ++i)
#pragma unroll
      for (int r = 0; r < 4; ++r) {
        const int row = wm * 64 + i * 16 + quad * 4 + r;
        const float l = red[256 + row] + red[256 + 128 + row];
        stats[(size_t)(row0 + row) * 32 + blockIdx.x] =
            make_float2(mrow[i][r], l);
      }
  }
}

// ---------------------------------------------------------------------------
// proj: qk = x Wqk^T + bias, split-i8 3-MFMA, bias + int16-grid quant epilogue.
// R10: same double-buffer + counted vmcnt + chunk swizzle as gemm_s_stats.
__global__ __launch_bounds__(256, 2) void gemm_proj_i8(
    const int8_t* __restrict__ Ahi, const int8_t* __restrict__ Alo,
    const int8_t* __restrict__ Bhi, const int8_t* __restrict__ Blo,
    const float* __restrict__ biasQ, const float* __restrict__ biasK,
    int8_t* __restrict__ Ch, int8_t* __restrict__ Cl)
{
  __shared__ __align__(16) int8_t sAh[2][128 * 64];
  __shared__ __align__(16) int8_t sAl[2][128 * 64];
  __shared__ __align__(16) int8_t sBh[2][128 * 64];
  __shared__ __align__(16) int8_t sBl[2][128 * 64];

  const int tid  = threadIdx.x;
  const int wave = tid >> 6;
  const int lane = tid & 63;
  const int quad = lane >> 4;
  const int t16  = lane & 15;
  const int wm   = wave & 1;
  const int wn   = wave >> 1;
  const int row0 = blockIdx.y * 128;
  const int col0 = blockIdx.x * 128;

  const int seg  = lane & 3;
  const int rsub = lane >> 2;
  const int segS = seg ^ (rsub & 3);
  const int rch  = (quad ^ (t16 & 3)) * 16;

  int4v hh[4][4], cc[4][4];
#pragma unroll
  for (int i = 0; i < 4; ++i)
#pragma unroll
    for (int j = 0; j < 4; ++j) {
      hh[i][j] = (int4v){0, 0, 0, 0};
      cc[i][j] = (int4v){0, 0, 0, 0};
    }

  auto stage_k = [&](int ks, int b) {
    const int k0 = ks * 64;
#pragma unroll
    for (int r = 0; r < 2; ++r) {
      const int trow = r * 64 + wave * 16;
      const size_t goffA = (size_t)(row0 + trow + rsub) * 1024 + k0 + segS * 16;
      const size_t goffB = (size_t)(col0 + trow + rsub) * 1024 + k0 + segS * 16;
      GLOAD_LDS16(Ahi + goffA, &sAh[b][trow * 64]);
      GLOAD_LDS16(Alo + goffA, &sAl[b][trow * 64]);
      GLOAD_LDS16(Bhi + goffB, &sBh[b][trow * 64]);
      GLOAD_LDS16(Blo + goffB, &sBl[b][trow * 64]);
    }
  };

  stage_k(0, 0);
  int buf = 0;
  for (int ks = 0; ks < 16; ++ks) {
    if (ks < 15) {
      stage_k(ks + 1, buf ^ 1);
      asm volatile("s_waitcnt vmcnt(8)" ::: "memory");
    } else {
      asm volatile("s_waitcnt vmcnt(0)" ::: "memory");
    }
    barrier_raw();

    int4v ah[4], al[4], bh[4], bl[4];
#pragma unroll
    for (int i = 0; i < 4; ++i) {
      const int ao = (wm * 64 + i * 16 + t16) * 64 + rch;
      ah[i] = *(const int4v*)&sAh[buf][ao];
      al[i] = *(const int4v*)&sAl[buf][ao];
    }
#pragma unroll
    for (int j = 0; j < 4; ++j) {
      const int bo = (wn * 64 + j * 16 + t16) * 64 + rch;
      bh[j] = *(const int4v*)&sBh[buf][bo];
      bl[j] = *(const int4v*)&sBl[buf][bo];
    }

#pragma unroll
    for (int i = 0; i < 4; ++i)
#pragma unroll
      for (int j = 0; j < 4; ++j) {
        hh[i][j] = __builtin_amdgcn_mfma_i32_16x16x64_i8(ah[i], bh[j], hh[i][j], 0, 0, 0);
        cc[i][j] = __builtin_amdgcn_mfma_i32_16x16x64_i8(ah[i], bl[j], cc[i][j], 0, 0, 0);
        cc[i][j] = __builtin_amdgcn_mfma_i32_16x16x64_i8(al[i], bh[j], cc[i][j], 0, 0, 0);
      }
    barrier_raw();
    buf ^= 1;
  }

#pragma unroll
  for (int i = 0; i < 4; ++i) {
#pragma unroll
    for (int j = 0; j < 4; ++j) {
      const int ccol = col0 + wn * 64 + j * 16 + t16;
      const float* bp = (ccol < 1024) ? biasQ : (biasK - 1024);
#pragma unroll
      for (int r = 0; r < 4; ++r) {
        const int crow = row0 + wm * 64 + i * 16 + quad * 4 + r;
        float v = P_HH * (float)hh[i][j][r] + P_X * (float)cc[i][j][r] + bp[ccol];
        int hi = (int)lrintf(v * INV_S256);
        hi = hi > 127 ? 127 : (hi < -127 ? -127 : hi);
        int lo = (int)lrintf(v * INV_S - 256.0f * (float)hi);
        lo = lo > 127 ? 127 : (lo < -127 ? -127 : lo);
        Ch[(size_t)crow * 2048 + ccol] = (int8_t)hi;
        Cl[(size_t)crow * 2048 + ccol] = (int8_t)lo;
      }
    }
  }
}

// ---------------------------------------------------------------------------
// AV: out = sum_t beta_t (E_t x). 512 threads, two wave-groups (z = wave>>2)
// doing in-block split-K=2; beta from stats in the prologue (LDS); direct
// fp32 store. R10: double-buffered stage (64 KB), prefetch-next + counted
// vmcnt(4), raw barriers, chunk swizzle on the 64-B LDS rows.
__global__ __launch_bounds__(512) void gemm_av(
    const uint16_t* __restrict__ E, const uint16_t* __restrict__ B,
    const float2* __restrict__ stats, float* __restrict__ out)
{
  __shared__ __align__(16) uint16_t stage[2][16384];  // 64 KB: [buf][z][sA|sB]
  __shared__ float betaS[128 * 33];                   // padded vs conflicts

  const int L      = blockIdx.x;        // 0..255
  const int xcd    = L & 7;
  const int rest   = L >> 3;            // 0..31
  const int colb   = rest & 7;          // 0..7
  const int bandHi = rest >> 3;         // 0..3
  const int band   = xcd + 8 * bandHi;  // 0..31
  const int row0   = band * 128;
  const int col0   = colb * 128;

  const int tid  = threadIdx.x;
  const int wave = tid >> 6;
  const int z    = wave >> 2;           // wave-group = K-half
  const int gw   = wave & 3;            // group-local wave
  const int lane = tid & 63;
  const int quad = lane >> 4;
  const int t16  = lane & 15;
  const int wm   = gw & 1;
  const int wn   = gw >> 1;
  const int seg  = lane & 3;
  const int rsub = lane >> 2;
  const int segS = seg ^ (rsub & 3);      // swizzled source chunk
  const int rch8 = (quad ^ (t16 & 3)) * 8; // swizzled read chunk (halves)

  // ---- beta prologue: threads 0..127, one row each ------------------------
  if (tid < 128) {
    const int row = row0 + tid;
    float2 st[32];
    float m = -3.0e38f;
#pragma unroll
    for (int t = 0; t < 32; ++t) {
      st[t] = stats[(size_t)row * 32 + t];
      m = fmaxf(m, st[t].x);
    }
    float l = 0.f;
#pragma unroll
    for (int t = 0; t < 32; ++t) l += st[t].y * __expf(st[t].x - m);
    const float inv = 1.0f / l;
#pragma unroll
    for (int t = 0; t < 32; ++t)
      betaS[tid * 33 + t] = __expf(st[t].x - m) * inv;
  }
  __syncthreads();

  float4v acc[4][4];
#pragma unroll
  for (int i = 0; i < 4; ++i)
#pragma unroll
    for (int j = 0; j < 4; ++j)
      acc[i][j] = (float4v){0.f, 0.f, 0.f, 0.f};

  // step s in [0,64): t = z*16 + (s>>2), kk = s&3
  auto stage_s = [&](int s, int b) {
    const int k0 = (z * 16 + (s >> 2)) * 128 + (s & 3) * 32;
    uint16_t* sA = &stage[b][z * 8192];
    uint16_t* sB = &stage[b][z * 8192 + 4096];
#pragma unroll
    for (int r = 0; r < 2; ++r) {
      const int trow = r * 64 + gw * 16;
      const size_t goffA = (size_t)(row0 + trow + rsub) * 4096 + k0 + segS * 8;
      const size_t goffB = (size_t)(col0 + trow + rsub) * 4096 + k0 + segS * 8;
      GLOAD_LDS16(E + goffA, &sA[trow * 32]);
      GLOAD_LDS16(B + goffB, &sB[trow * 32]);
    }
  };

  stage_s(0, 0);
  int buf = 0;
  for (int s = 0; s < 64; ++s) {
    if (s < 63) {
      stage_s(s + 1, buf ^ 1);
      asm volatile("s_waitcnt vmcnt(4)" ::: "memory");  // my stage(s) landed
    } else {
      asm volatile("s_waitcnt vmcnt(0)" ::: "memory");
    }
    barrier_raw();

    const int t = z * 16 + (s >> 2);
    _Float16 bb[4];
#pragma unroll
    for (int i = 0; i < 4; ++i)
      bb[i] = (_Float16)betaS[(wm * 64 + i * 16 + t16) * 33 + t];

    const uint16_t* sA = &stage[buf][z * 8192];
    const uint16_t* sB = &stage[buf][z * 8192 + 4096];

    half8 af[4], bf[4];
#pragma unroll
    for (int i = 0; i < 4; ++i) {
      af[i] = *(const half8*)&sA[(wm * 64 + i * 16 + t16) * 32 + rch8];
      half8 bs;
#pragma unroll
      for (int c = 0; c < 8; ++c) bs[c] = bb[i];
      af[i] = af[i] * bs;
    }
#pragma unroll
    for (int j = 0; j < 4; ++j)
      bf[j] = *(const half8*)&sB[(wn * 64 + j * 16 + t16) * 32 + rch8];

#pragma unroll
    for (int i = 0; i < 4; ++i)
#pragma unroll
      for (int j = 0; j < 4; ++j)
        acc[i][j] = __builtin_amdgcn_mfma_f32_16x16x32_f16(af[i], bf[j], acc[i][j], 0, 0, 0);

    barrier_raw();  // reads of buf done before it is restaged
    buf ^= 1;
  }

  // ---- combine group1 -> group0 via LDS (two 32 KB halves) ----------------
  float* xfer = (float*)stage;  // 8192 floats
#pragma unroll
  for (int h = 0; h < 2; ++h) {
    if (z == 1) {
#pragma unroll
      for (int i = 2 * h; i < 2 * h + 2; ++i)
#pragma unroll
        for (int j = 0; j < 4; ++j)
#pragma unroll
          for (int r = 0; r < 4; ++r) {
            const int e = (i - 2 * h) * 16 + j * 4 + r;
            xfer[e * 256 + gw * 64 + lane] = acc[i][j][r];
          }
    }
    __syncthreads();
    if (z == 0) {
#pragma unroll
      for (int i = 2 * h; i < 2 * h + 2; ++i)
#pragma unroll
        for (int j = 0; j < 4; ++j)
#pragma unroll
          for (int r = 0; r < 4; ++r) {
            const int e = (i - 2 * h) * 16 + j * 4 + r;
            acc[i][j][r] += xfer[e * 256 + gw * 64 + lane];
          }
    }
    __syncthreads();
  }

  // ---- store (group0 only) ------------------------------------------------
  if (z == 0) {
#pragma unroll
    for (int i = 0; i < 4; ++i) {
#pragma unroll
      for (int j = 0; j < 4; ++j) {
        const int ccol = col0 + wn * 64 + j * 16 + t16;
#pragma unroll
        for (int r = 0; r < 4; ++r) {
          const int crow = row0 + wm * 64 + i * 16 + quad * 4 + r;
          out[(size_t)crow * 1024 + ccol] = acc[i][j][r];
        }
      }
    }
  }
}

// ---------------------------------------------------------------------------
// Fused quant + transpose-cast.
// Blocks 0..6143: quantize x (+-6 grid) / Wq / Wk (+-0.25 grid) to i8 planes.
// Blocks 6144..10239: transpose-cast x -> xT fp16 (32x32 tiles, 256 thr).
__global__ __launch_bounds__(256) void quantT(
    const float* __restrict__ x, const float* __restrict__ Wq,
    const float* __restrict__ Wk,
    int8_t* __restrict__ xhi, int8_t* __restrict__ xlo,
    int8_t* __restrict__ whi, int8_t* __restrict__ wlo,
    uint16_t* __restrict__ xT)
{
  if (blockIdx.x < 6144) {
    int i = blockIdx.x * 256 + threadIdx.x;  // 0..1572863
    const float* src; int8_t* dh; int8_t* dl; int idx; float s256, s;
    if (i < 1048576)      { src = x;  idx = i;           dh = xhi; dl = xlo;
                            s256 = INV_S256; s = INV_S; }
    else if (i < 1310720) { src = Wq; idx = i - 1048576; dh = whi; dl = wlo;
                            s256 = 512.0f; s = 131072.0f; }
    else                  { src = Wk; idx = i - 1310720; dh = whi + 1048576;
                            dl = wlo + 1048576; s256 = 512.0f; s = 131072.0f; }
    float4 v = ((const float4*)src)[idx];
    float vv[4] = {v.x, v.y, v.z, v.w};
    int hp = 0, lp = 0;
#pragma unroll
    for (int c = 0; c < 4; ++c) {
      int h = (int)lrintf(vv[c] * s256);
      h = h > 127 ? 127 : (h < -127 ? -127 : h);
      int l = (int)lrintf(vv[c] * s - 256.0f * (float)h);
      l = l > 127 ? 127 : (l < -127 ? -127 : l);
      hp |= (h & 0xff) << (8 * c);
      lp |= (l & 0xff) << (8 * c);
    }
    ((int*)dh)[idx] = hp;
    ((int*)dl)[idx] = lp;
  } else {
    __shared__ float tile[32][33];
    const int tb = blockIdx.x - 6144;   // 0..4095
    const int bx = tb & 31;             // D/32
    const int by = tb >> 5;             // N/32
    const int tx = threadIdx.x & 31;
    const int ty = threadIdx.x >> 5;    // 0..7
#pragma unroll
    for (int p = 0; p < 4; ++p) {
      const int row = by * 32 + ty + p * 8;
      tile[ty + p * 8][tx] = x[(size_t)row * 1024 + bx * 32 + tx];
    }
    __syncthreads();
#pragma unroll
    for (int p = 0; p < 4; ++p) {
      const int oc = ty + p * 8;  // local col in x == local row in xT
      __half hv = __float2half_rn(tile[tx][oc]);
      xT[(size_t)(bx * 32 + oc) * 4096 + by * 32 + tx] = *(uint16_t*)&hv;
    }
  }
}

extern "C" void kernel_launch(void* const* d_in, const int* in_sizes, int n_in,
                              void* d_out, int out_size, void* d_ws, size_t ws_size,
                              hipStream_t stream) {
  const int N = 4096, D = 1024;
  const float* x  = (const float*)d_in[0];
  const float* Wq = (const float*)d_in[1];
  const float* bq = (const float*)d_in[2];
  const float* Wk = (const float*)d_in[3];
  const float* bk = (const float*)d_in[4];
  float* out = (float*)d_out;

  // workspace layout (MiB offsets)
  char* w = (char*)d_ws;
  const size_t MiB = 1024 * 1024;
  int8_t*    xq_hi  = (int8_t*)   (w + 0  * MiB);  // [N x D]
  int8_t*    xq_lo  = (int8_t*)   (w + 4  * MiB);
  int8_t*    Wqk_hi = (int8_t*)   (w + 8  * MiB);  // [2048 x D]
  int8_t*    Wqk_lo = (int8_t*)   (w + 10 * MiB);
  int8_t*    qk_hi  = (int8_t*)   (w + 12 * MiB);  // [N x 2048]
  int8_t*    qk_lo  = (int8_t*)   (w + 20 * MiB);
  _Float16*  E      = (_Float16*) (w + 36 * MiB);  // [N x N] fp16, 32 MiB
  float2*    stats  = (float2*)   (w + 68 * MiB);  // [N x 32] (m,l), 1 MiB
  uint16_t*  xTh    = (uint16_t*) (w + 72 * MiB);  // [D x N] fp16
  // total 80 MiB

  // 1) fused quantization + transpose-cast  (6144 + 4096 blocks)
  quantT<<<10240, 256, 0, stream>>>(x, Wq, Wk, xq_hi, xq_lo, Wqk_hi, Wqk_lo,
                                    xTh);

  // 2) fused qk projection: i8 16x16x64, 3-MFMA, bias+quant epilogue
  gemm_proj_i8<<<dim3(2048 / 128, N / 128), 256, 0, stream>>>(
      xq_hi, xq_lo, Wqk_hi, Wqk_lo, bq, bk, qk_hi, qk_lo);

  // 3) S = q k^T + tile softmax stats -> E fp16, stats (m_t, l_t)
  gemm_s_stats<<<dim3(N / 128, N / 128), 256, 0, stream>>>(
      qk_hi, qk_lo, qk_hi + 1024, qk_lo + 1024, E, stats);

  // 4) out = sum_t beta_t (E_t x): beta prologue + in-block split-K=2
  gemm_av<<<256, 512, 0, stream>>>((const uint16_t*)E, xTh, stats, out);

  (void)in_sizes; (void)n_in; (void)out_size; (void)ws_size;
}

// Round 2
// 218.931 us; speedup vs baseline: 1.1136x; 1.0132x over previous
//
#include <hip/hip_runtime.h>
#include <hip/hip_bf16.h>
#include <hip/hip_fp16.h>
#include <stdint.h>

// ---------------------------------------------------------------------------
// CLIPAttentionPooling. R11: single-barrier 2-phase loops + 32-bit address
// strength reduction. R10 post-mortem: SQ_LDS_BANK_CONFLICT = 4*n_ds_read_b128
// exactly (structural b128 overhead, not conflicts); s_stats flat at 77us with
// MfmaUtil 27 + VALU 21 + LDS ~25 ~= fully serialized phases.
// Changes:
//   * All 3 GEMMs: ONE vmcnt(0)+s_barrier per K-step (catalog minimum-2-phase:
//     STAGE(next) -> ds_read -> MFMA -> vmcnt -> barrier), stage latency hides
//     under reads+MFMA. Was 2 barriers/step.
//   * 32-bit precomputed lane offsets + k0 (kills per-step 64-bit addr VALU).
//   * Dropped the R10 chunk swizzle in s_stats/proj (64-B rows are already
//     bank-balanced; counter proved it a no-op).
//   * gemm_av: K-chunk 32->64 (32 steps, 32 barriers vs 128), 128-B LDS rows
//     with a REAL both-sides chunk-rotate swizzle ((c+row)&7), stage(0) issued
//     before the beta prologue so HBM latency hides under the exp work.
//   * s_setprio(1) around MFMA clusters.
// ---------------------------------------------------------------------------

using half8   = __attribute__((ext_vector_type(8))) _Float16;
using float4v = __attribute__((ext_vector_type(4))) float;
using int4v   = __attribute__((ext_vector_type(4))) int;

// q/k int16 grid: covers +-6.0, v = QS*(256*hi+lo)
#define QS        (6.0f / 32768.0f)
#define INV_S     (32768.0f / 6.0f)
#define INV_S256  (128.0f / 6.0f)
#define C_HH      (65536.0f * QS * QS)
#define C_X       (256.0f * QS * QS)

// x grid: +-6.0 ; W grid: +-0.25
#define SX        (6.0f / 32768.0f)
#define SW        (0.25f / 32768.0f)
#define P_HH      (65536.0f * SX * SW)
#define P_X       (256.0f * SX * SW)

#define GLOAD_LDS16(gptr, ldsptr)                                              \
  __builtin_amdgcn_global_load_lds(                                            \
      (__attribute__((address_space(1))) void*)(uintptr_t)(gptr),              \
      (__attribute__((address_space(3))) void*)(unsigned)(uintptr_t)(ldsptr),  \
      16, 0, 0)

__device__ __forceinline__ void barrier_raw() {
  asm volatile("" ::: "memory");
  __builtin_amdgcn_s_barrier();
  asm volatile("" ::: "memory");
}

// ---------------------------------------------------------------------------
// S GEMM + tile softmax stats. Split-i8 16x16x64, 128x128 tile, BK=64.
// R11: single-barrier K-loop, 32-bit offsets, linear LDS chunks.
__global__ __launch_bounds__(256, 2) void gemm_s_stats(
    const int8_t* __restrict__ Ahi, const int8_t* __restrict__ Alo,
    const int8_t* __restrict__ Bhi, const int8_t* __restrict__ Blo,
    _Float16* __restrict__ E, float2* __restrict__ stats)
{
  __shared__ __align__(16) int8_t sAh[2][128 * 64];
  __shared__ __align__(16) int8_t sAl[2][128 * 64];
  __shared__ __align__(16) int8_t sBh[2][128 * 64];
  __shared__ __align__(16) int8_t sBl[2][128 * 64];

  const int tid  = threadIdx.x;
  const int wave = tid >> 6;
  const int lane = tid & 63;
  const int quad = lane >> 4;
  const int t16  = lane & 15;
  const int wm   = wave & 1;
  const int wn   = wave >> 1;
  const int row0 = blockIdx.y * 128;
  const int col0 = blockIdx.x * 128;

  const int seg  = lane & 3;   // 16B chunk within 64B row
  const int rsub = lane >> 2;  // row within 16-row stripe

  // 32-bit lane offsets (bytes), loop-invariant; +k0 per step.
  const int offA0 = (row0 + wave * 16 + rsub) * 2048 + seg * 16;
  const int offA1 = offA0 + 64 * 2048;
  const int offB0 = (col0 + wave * 16 + rsub) * 2048 + seg * 16;
  const int offB1 = offB0 + 64 * 2048;
  const int ldsT0 = (wave * 16) * 64;        // bytes into a plane
  const int ldsT1 = (64 + wave * 16) * 64;

  int4v hh[4][4], cc[4][4];
#pragma unroll
  for (int i = 0; i < 4; ++i)
#pragma unroll
    for (int j = 0; j < 4; ++j) {
      hh[i][j] = (int4v){0, 0, 0, 0};
      cc[i][j] = (int4v){0, 0, 0, 0};
    }

  auto stage_k = [&](int ks, int b) {
    const int k0 = ks * 64;
    GLOAD_LDS16(Ahi + offA0 + k0, &sAh[b][ldsT0]);
    GLOAD_LDS16(Ahi + offA1 + k0, &sAh[b][ldsT1]);
    GLOAD_LDS16(Alo + offA0 + k0, &sAl[b][ldsT0]);
    GLOAD_LDS16(Alo + offA1 + k0, &sAl[b][ldsT1]);
    GLOAD_LDS16(Bhi + offB0 + k0, &sBh[b][ldsT0]);
    GLOAD_LDS16(Bhi + offB1 + k0, &sBh[b][ldsT1]);
    GLOAD_LDS16(Blo + offB0 + k0, &sBl[b][ldsT0]);
    GLOAD_LDS16(Blo + offB1 + k0, &sBl[b][ldsT1]);
  };

  stage_k(0, 0);
  asm volatile("s_waitcnt vmcnt(0)" ::: "memory");
  barrier_raw();

  int buf = 0;
  for (int ks = 0; ks < 16; ++ks) {
    if (ks < 15) stage_k(ks + 1, buf ^ 1);  // prefetch; latency hides below

    int4v ah[4], al[4], bh[4], bl[4];
#pragma unroll
    for (int i = 0; i < 4; ++i) {
      const int ao = (wm * 64 + i * 16 + t16) * 64 + quad * 16;
      ah[i] = *(const int4v*)&sAh[buf][ao];
      al[i] = *(const int4v*)&sAl[buf][ao];
    }
#pragma unroll
    for (int j = 0; j < 4; ++j) {
      const int bo = (wn * 64 + j * 16 + t16) * 64 + quad * 16;
      bh[j] = *(const int4v*)&sBh[buf][bo];
      bl[j] = *(const int4v*)&sBl[buf][bo];
    }

    __builtin_amdgcn_s_setprio(1);
#pragma unroll
    for (int i = 0; i < 4; ++i)
#pragma unroll
      for (int j = 0; j < 4; ++j) {
        hh[i][j] = __builtin_amdgcn_mfma_i32_16x16x64_i8(ah[i], bh[j], hh[i][j], 0, 0, 0);
        cc[i][j] = __builtin_amdgcn_mfma_i32_16x16x64_i8(ah[i], bl[j], cc[i][j], 0, 0, 0);
        cc[i][j] = __builtin_amdgcn_mfma_i32_16x16x64_i8(al[i], bh[j], cc[i][j], 0, 0, 0);
      }
    __builtin_amdgcn_s_setprio(0);

    if (ks < 15) asm volatile("s_waitcnt vmcnt(0)" ::: "memory");
    barrier_raw();  // one barrier/step: stage landed AND reads consumed
    buf ^= 1;
  }

  // ---- epilogue: tile-local softmax stats (R8-verified) --------------------
  float* red = (float*)sAh;  // buf-0 region; final reads were from buf 1

  float vv[4][4][4];
  float rmax[4][4];
#pragma unroll
  for (int i = 0; i < 4; ++i)
#pragma unroll
    for (int r = 0; r < 4; ++r) {
      float mx = -3.0e38f;
#pragma unroll
      for (int j = 0; j < 4; ++j) {
        float v = C_HH * (float)hh[i][j][r] + C_X * (float)cc[i][j][r];
        vv[i][j][r] = v;
        mx = fmaxf(mx, v);
      }
      mx = fmaxf(mx, __shfl_xor(mx, 1));
      mx = fmaxf(mx, __shfl_xor(mx, 2));
      mx = fmaxf(mx, __shfl_xor(mx, 4));
      mx = fmaxf(mx, __shfl_xor(mx, 8));
      rmax[i][r] = mx;
    }
  if (t16 == 0) {
#pragma unroll
    for (int i = 0; i < 4; ++i)
#pragma unroll
      for (int r = 0; r < 4; ++r)
        red[wn * 128 + wm * 64 + i * 16 + quad * 4 + r] = rmax[i][r];
  }
  __syncthreads();

  float mrow[4][4];
#pragma unroll
  for (int i = 0; i < 4; ++i)
#pragma unroll
    for (int r = 0; r < 4; ++r) {
      const int row = wm * 64 + i * 16 + quad * 4 + r;
      mrow[i][r] = fmaxf(red[row], red[128 + row]);
    }

  float rsum[4][4];
#pragma unroll
  for (int i = 0; i < 4; ++i)
#pragma unroll
    for (int r = 0; r < 4; ++r) {
      float s = 0.f;
#pragma unroll
      for (int j = 0; j < 4; ++j) {
        float e = __expf(vv[i][j][r] - mrow[i][r]);
        vv[i][j][r] = e;
        s += e;
      }
      s += __shfl_xor(s, 1);
      s += __shfl_xor(s, 2);
      s += __shfl_xor(s, 4);
      s += __shfl_xor(s, 8);
      rsum[i][r] = s;
    }
  if (t16 == 0) {
#pragma unroll
    for (int i = 0; i < 4; ++i)
#pragma unroll
      for (int r = 0; r < 4; ++r)
        red[256 + wn * 128 + wm * 64 + i * 16 + quad * 4 + r] = rsum[i][r];
  }
  __syncthreads();

#pragma unroll
  for (int i = 0; i < 4; ++i) {
#pragma unroll
    for (int j = 0; j < 4; ++j) {
#pragma unroll
      for (int r = 0; r < 4; ++r) {
        const int crow = row0 + wm * 64 + i * 16 + quad * 4 + r;
        const int ccol = col0 + wn * 64 + j * 16 + t16;
        E[(size_t)crow * 4096 + ccol] = (_Float16)vv[i][j][r];
      }
    }
  }
  if (wn == 0 && t16 == 0) {
#pragma unroll
    for (int i = 0; i < 4; ++i)
#pragma unroll
      for (int r = 0; r < 4; ++r) {
        const int row = wm * 64 + i * 16 + quad * 4 + r;
        const float l = red[256 + row] + red[256 + 128 + row];
        stats[(size_t)(row0 + row) * 32 + blockIdx.x] =
            make_float2(mrow[i][r], l);
      }
  }
}

// ---------------------------------------------------------------------------
// proj: qk = x Wqk^T + bias, split-i8 3-MFMA, bias + int16-grid quant epilogue.
// R11: same single-barrier loop + 32-bit offsets as gemm_s_stats.
__global__ __launch_bounds__(256, 2) void gemm_proj_i8(
    const int8_t* __restrict__ Ahi, const int8_t* __restrict__ Alo,
    const int8_t* __restrict__ Bhi, const int8_t* __restrict__ Blo,
    const float* __restrict__ biasQ, const float* __restrict__ biasK,
    int8_t* __restrict__ Ch, int8_t* __restrict__ Cl)
{
  __shared__ __align__(16) int8_t sAh[2][128 * 64];
  __shared__ __align__(16) int8_t sAl[2][128 * 64];
  __shared__ __align__(16) int8_t sBh[2][128 * 64];
  __shared__ __align__(16) int8_t sBl[2][128 * 64];

  const int tid  = threadIdx.x;
  const int wave = tid >> 6;
  const int lane = tid & 63;
  const int quad = lane >> 4;
  const int t16  = lane & 15;
  const int wm   = wave & 1;
  const int wn   = wave >> 1;
  const int row0 = blockIdx.y * 128;
  const int col0 = blockIdx.x * 128;

  const int seg  = lane & 3;
  const int rsub = lane >> 2;

  const int offA0 = (row0 + wave * 16 + rsub) * 1024 + seg * 16;
  const int offA1 = offA0 + 64 * 1024;
  const int offB0 = (col0 + wave * 16 + rsub) * 1024 + seg * 16;
  const int offB1 = offB0 + 64 * 1024;
  const int ldsT0 = (wave * 16) * 64;
  const int ldsT1 = (64 + wave * 16) * 64;

  int4v hh[4][4], cc[4][4];
#pragma unroll
  for (int i = 0; i < 4; ++i)
#pragma unroll
    for (int j = 0; j < 4; ++j) {
      hh[i][j] = (int4v){0, 0, 0, 0};
      cc[i][j] = (int4v){0, 0, 0, 0};
    }

  auto stage_k = [&](int ks, int b) {
    const int k0 = ks * 64;
    GLOAD_LDS16(Ahi + offA0 + k0, &sAh[b][ldsT0]);
    GLOAD_LDS16(Ahi + offA1 + k0, &sAh[b][ldsT1]);
    GLOAD_LDS16(Alo + offA0 + k0, &sAl[b][ldsT0]);
    GLOAD_LDS16(Alo + offA1 + k0, &sAl[b][ldsT1]);
    GLOAD_LDS16(Bhi + offB0 + k0, &sBh[b][ldsT0]);
    GLOAD_LDS16(Bhi + offB1 + k0, &sBh[b][ldsT1]);
    GLOAD_LDS16(Blo + offB0 + k0, &sBl[b][ldsT0]);
    GLOAD_LDS16(Blo + offB1 + k0, &sBl[b][ldsT1]);
  };

  stage_k(0, 0);
  asm volatile("s_waitcnt vmcnt(0)" ::: "memory");
  barrier_raw();

  int buf = 0;
  for (int ks = 0; ks < 16; ++ks) {
    if (ks < 15) stage_k(ks + 1, buf ^ 1);

    int4v ah[4], al[4], bh[4], bl[4];
#pragma unroll
    for (int i = 0; i < 4; ++i) {
      const int ao = (wm * 64 + i * 16 + t16) * 64 + quad * 16;
      ah[i] = *(const int4v*)&sAh[buf][ao];
      al[i] = *(const int4v*)&sAl[buf][ao];
    }
#pragma unroll
    for (int j = 0; j < 4; ++j) {
      const int bo = (wn * 64 + j * 16 + t16) * 64 + quad * 16;
      bh[j] = *(const int4v*)&sBh[buf][bo];
      bl[j] = *(const int4v*)&sBl[buf][bo];
    }

    __builtin_amdgcn_s_setprio(1);
#pragma unroll
    for (int i = 0; i < 4; ++i)
#pragma unroll
      for (int j = 0; j < 4; ++j) {
        hh[i][j] = __builtin_amdgcn_mfma_i32_16x16x64_i8(ah[i], bh[j], hh[i][j], 0, 0, 0);
        cc[i][j] = __builtin_amdgcn_mfma_i32_16x16x64_i8(ah[i], bl[j], cc[i][j], 0, 0, 0);
        cc[i][j] = __builtin_amdgcn_mfma_i32_16x16x64_i8(al[i], bh[j], cc[i][j], 0, 0, 0);
      }
    __builtin_amdgcn_s_setprio(0);

    if (ks < 15) asm volatile("s_waitcnt vmcnt(0)" ::: "memory");
    barrier_raw();
    buf ^= 1;
  }

#pragma unroll
  for (int i = 0; i < 4; ++i) {
#pragma unroll
    for (int j = 0; j < 4; ++j) {
      const int ccol = col0 + wn * 64 + j * 16 + t16;
      const float* bp = (ccol < 1024) ? biasQ : (biasK - 1024);
#pragma unroll
      for (int r = 0; r < 4; ++r) {
        const int crow = row0 + wm * 64 + i * 16 + quad * 4 + r;
        float v = P_HH * (float)hh[i][j][r] + P_X * (float)cc[i][j][r] + bp[ccol];
        int hi = (int)lrintf(v * INV_S256);
        hi = hi > 127 ? 127 : (hi < -127 ? -127 : hi);
        int lo = (int)lrintf(v * INV_S - 256.0f * (float)hi);
        lo = lo > 127 ? 127 : (lo < -127 ? -127 : lo);
        Ch[(size_t)crow * 2048 + ccol] = (int8_t)hi;
        Cl[(size_t)crow * 2048 + ccol] = (int8_t)lo;
      }
    }
  }
}

// ---------------------------------------------------------------------------
// AV: out = sum_t beta_t (E_t x). 512 threads, two wave-groups (z = wave>>2)
// doing in-block split-K=2. R11: K-chunk 64 (32 steps, 1 barrier each),
// 128-B LDS rows with both-sides chunk-rotate swizzle, stage(0) before the
// beta prologue, 32-bit offsets.
__global__ __launch_bounds__(512) void gemm_av(
    const uint16_t* __restrict__ E, const uint16_t* __restrict__ B,
    const float2* __restrict__ stats, float* __restrict__ out)
{
  // [buf][z][ A:128x64h | B:128x64h ] = 2*2*16384 halves = 128 KB
  __shared__ __align__(16) uint16_t stg[2][2][16384];
  __shared__ float betaS[128 * 33];

  const int L      = blockIdx.x;        // 0..255
  const int xcd    = L & 7;
  const int rest   = L >> 3;            // 0..31
  const int colb   = rest & 7;          // 0..7
  const int bandHi = rest >> 3;         // 0..3
  const int band   = xcd + 8 * bandHi;  // 0..31
  const int row0   = band * 128;
  const int col0   = colb * 128;

  const int tid  = threadIdx.x;
  const int wave = tid >> 6;
  const int z    = wave >> 2;           // wave-group = K-half
  const int gw   = wave & 3;            // group-local wave
  const int lane = tid & 63;
  const int quad = lane >> 4;
  const int t16  = lane & 15;
  const int wm   = gw & 1;
  const int wn   = gw >> 1;

  const int c8   = lane & 7;            // 16B-chunk within 128B row
  const int r8   = lane >> 3;           // row within 8-row stripe
  const int srcC = (c8 - r8) & 7;       // rotate: LDS[row][c] = glob[(c-row)&7]

  // stage offsets in halves, loop-invariant; +k0h per step.
  int offA[4], offB[4];
#pragma unroll
  for (int r = 0; r < 4; ++r) {
    offA[r] = (row0 + r * 32 + gw * 8 + r8) * 4096 + srcC * 8;
    offB[r] = (col0 + r * 32 + gw * 8 + r8) * 4096 + srcC * 8;
  }

  // step s in [0,32): t = z*16 + (s>>1), half = s&1 (64 cols each)
  auto stage_s = [&](int s, int b) {
    const int k0h = (z * 16 + (s >> 1)) * 128 + (s & 1) * 64;
    uint16_t* sA = &stg[b][z][0];
    uint16_t* sB = &stg[b][z][8192];
#pragma unroll
    for (int r = 0; r < 4; ++r) {
      GLOAD_LDS16(E + offA[r] + k0h, &sA[(r * 32 + gw * 8) * 64]);
      GLOAD_LDS16(B + offB[r] + k0h, &sB[(r * 32 + gw * 8) * 64]);
    }
  };

  stage_s(0, 0);  // issue first tile before prologue; latency hides under exp

  // ---- beta prologue: threads 0..127, one row each ------------------------
  if (tid < 128) {
    const int row = row0 + tid;
    float2 st[32];
    float m = -3.0e38f;
#pragma unroll
    for (int t = 0; t < 32; ++t) {
      st[t] = stats[(size_t)row * 32 + t];
      m = fmaxf(m, st[t].x);
    }
    float l = 0.f;
#pragma unroll
    for (int t = 0; t < 32; ++t) l += st[t].y * __expf(st[t].x - m);
    const float inv = 1.0f / l;
#pragma unroll
    for (int t = 0; t < 32; ++t)
      betaS[tid * 33 + t] = __expf(st[t].x - m) * inv;
  }
  asm volatile("s_waitcnt vmcnt(0)" ::: "memory");
  __syncthreads();  // covers betaS AND stage(0)

  float4v acc[4][4];
#pragma unroll
  for (int i = 0; i < 4; ++i)
#pragma unroll
    for (int j = 0; j < 4; ++j)
      acc[i][j] = (float4v){0.f, 0.f, 0.f, 0.f};

  int buf = 0;
  for (int s = 0; s < 32; ++s) {
    if (s < 31) stage_s(s + 1, buf ^ 1);

    const int t = z * 16 + (s >> 1);
    _Float16 bb[4];
#pragma unroll
    for (int i = 0; i < 4; ++i)
      bb[i] = (_Float16)betaS[(wm * 64 + i * 16 + t16) * 33 + t];

    const uint16_t* sA = &stg[buf][z][0];
    const uint16_t* sB = &stg[buf][z][8192];

    half8 af[2][4], bf[2][4];
#pragma unroll
    for (int ks = 0; ks < 2; ++ks) {
#pragma unroll
      for (int i = 0; i < 4; ++i) {
        const int row = wm * 64 + i * 16 + t16;
        const int ch  = (ks * 4 + quad + (t16 & 7)) & 7;
        af[ks][i] = *(const half8*)&sA[row * 64 + ch * 8];
        half8 bs;
#pragma unroll
        for (int c = 0; c < 8; ++c) bs[c] = bb[i];
        af[ks][i] = af[ks][i] * bs;
      }
#pragma unroll
      for (int j = 0; j < 4; ++j) {
        const int row = wn * 64 + j * 16 + t16;
        const int ch  = (ks * 4 + quad + (t16 & 7)) & 7;
        bf[ks][j] = *(const half8*)&sB[row * 64 + ch * 8];
      }
    }

    __builtin_amdgcn_s_setprio(1);
#pragma unroll
    for (int ks = 0; ks < 2; ++ks)
#pragma unroll
      for (int i = 0; i < 4; ++i)
#pragma unroll
        for (int j = 0; j < 4; ++j)
          acc[i][j] = __builtin_amdgcn_mfma_f32_16x16x32_f16(af[ks][i], bf[ks][j], acc[i][j], 0, 0, 0);
    __builtin_amdgcn_s_setprio(0);

    if (s < 31) asm volatile("s_waitcnt vmcnt(0)" ::: "memory");
    barrier_raw();
    buf ^= 1;
  }

  // ---- combine group1 -> group0 via LDS (two 32 KB halves) ----------------
  float* xfer = (float*)stg;  // buf-0 region; final reads were from buf 1
#pragma unroll
  for (int h = 0; h < 2; ++h) {
    if (z == 1) {
#pragma unroll
      for (int i = 2 * h; i < 2 * h + 2; ++i)
#pragma unroll
        for (int j = 0; j < 4; ++j)
#pragma unroll
          for (int r = 0; r < 4; ++r) {
            const int e = (i - 2 * h) * 16 + j * 4 + r;
            xfer[e * 256 + gw * 64 + lane] = acc[i][j][r];
          }
    }
    __syncthreads();
    if (z == 0) {
#pragma unroll
      for (int i = 2 * h; i < 2 * h + 2; ++i)
#pragma unroll
        for (int j = 0; j < 4; ++j)
#pragma unroll
          for (int r = 0; r < 4; ++r) {
            const int e = (i - 2 * h) * 16 + j * 4 + r;
            acc[i][j][r] += xfer[e * 256 + gw * 64 + lane];
          }
    }
    __syncthreads();
  }

  // ---- store (group0 only) ------------------------------------------------
  if (z == 0) {
#pragma unroll
    for (int i = 0; i < 4; ++i) {
#pragma unroll
      for (int j = 0; j < 4; ++j) {
        const int ccol = col0 + wn * 64 + j * 16 + t16;
#pragma unroll
        for (int r = 0; r < 4; ++r) {
          const int crow = row0 + wm * 64 + i * 16 + quad * 4 + r;
          out[(size_t)crow * 1024 + ccol] = acc[i][j][r];
        }
      }
    }
  }
}

// ---------------------------------------------------------------------------
// Fused quant + transpose-cast.
// Blocks 0..6143: quantize x (+-6 grid) / Wq / Wk (+-0.25 grid) to i8 planes.
// Blocks 6144..10239: transpose-cast x -> xT fp16 (32x32 tiles, 256 thr).
__global__ __launch_bounds__(256) void quantT(
    const float* __restrict__ x, const float* __restrict__ Wq,
    const float* __restrict__ Wk,
    int8_t* __restrict__ xhi, int8_t* __restrict__ xlo,
    int8_t* __restrict__ whi, int8_t* __restrict__ wlo,
    uint16_t* __restrict__ xT)
{
  if (blockIdx.x < 6144) {
    int i = blockIdx.x * 256 + threadIdx.x;  // 0..1572863
    const float* src; int8_t* dh; int8_t* dl; int idx; float s256, s;
    if (i < 1048576)      { src = x;  idx = i;           dh = xhi; dl = xlo;
                            s256 = INV_S256; s = INV_S; }
    else if (i < 1310720) { src = Wq; idx = i - 1048576; dh = whi; dl = wlo;
                            s256 = 512.0f; s = 131072.0f; }
    else                  { src = Wk; idx = i - 1310720; dh = whi + 1048576;
                            dl = wlo + 1048576; s256 = 512.0f; s = 131072.0f; }
    float4 v = ((const float4*)src)[idx];
    float vv[4] = {v.x, v.y, v.z, v.w};
    int hp = 0, lp = 0;
#pragma unroll
    for (int c = 0; c < 4; ++c) {
      int h = (int)lrintf(vv[c] * s256);
      h = h > 127 ? 127 : (h < -127 ? -127 : h);
      int l = (int)lrintf(vv[c] * s - 256.0f * (float)h);
      l = l > 127 ? 127 : (l < -127 ? -127 : l);
      hp |= (h & 0xff) << (8 * c);
      lp |= (l & 0xff) << (8 * c);
    }
    ((int*)dh)[idx] = hp;
    ((int*)dl)[idx] = lp;
  } else {
    __shared__ float tile[32][33];
    const int tb = blockIdx.x - 6144;   // 0..4095
    const int bx = tb & 31;             // D/32
    const int by = tb >> 5;             // N/32
    const int tx = threadIdx.x & 31;
    const int ty = threadIdx.x >> 5;    // 0..7
#pragma unroll
    for (int p = 0; p < 4; ++p) {
      const int row = by * 32 + ty + p * 8;
      tile[ty + p * 8][tx] = x[(size_t)row * 1024 + bx * 32 + tx];
    }
    __syncthreads();
#pragma unroll
    for (int p = 0; p < 4; ++p) {
      const int oc = ty + p * 8;  // local col in x == local row in xT
      __half hv = __float2half_rn(tile[tx][oc]);
      xT[(size_t)(bx * 32 + oc) * 4096 + by * 32 + tx] = *(uint16_t*)&hv;
    }
  }
}

extern "C" void kernel_launch(void* const* d_in, const int* in_sizes, int n_in,
                              void* d_out, int out_size, void* d_ws, size_t ws_size,
                              hipStream_t stream) {
  const int N = 4096, D = 1024;
  const float* x  = (const float*)d_in[0];
  const float* Wq = (const float*)d_in[1];
  const float* bq = (const float*)d_in[2];
  const float* Wk = (const float*)d_in[3];
  const float* bk = (const float*)d_in[4];
  float* out = (float*)d_out;

  // workspace layout (MiB offsets)
  char* w = (char*)d_ws;
  const size_t MiB = 1024 * 1024;
  int8_t*    xq_hi  = (int8_t*)   (w + 0  * MiB);  // [N x D]
  int8_t*    xq_lo  = (int8_t*)   (w + 4  * MiB);
  int8_t*    Wqk_hi = (int8_t*)   (w + 8  * MiB);  // [2048 x D]
  int8_t*    Wqk_lo = (int8_t*)   (w + 10 * MiB);
  int8_t*    qk_hi  = (int8_t*)   (w + 12 * MiB);  // [N x 2048]
  int8_t*    qk_lo  = (int8_t*)   (w + 20 * MiB);
  _Float16*  E      = (_Float16*) (w + 36 * MiB);  // [N x N] fp16, 32 MiB
  float2*    stats  = (float2*)   (w + 68 * MiB);  // [N x 32] (m,l), 1 MiB
  uint16_t*  xTh    = (uint16_t*) (w + 72 * MiB);  // [D x N] fp16
  // total 80 MiB

  // 1) fused quantization + transpose-cast  (6144 + 4096 blocks)
  quantT<<<10240, 256, 0, stream>>>(x, Wq, Wk, xq_hi, xq_lo, Wqk_hi, Wqk_lo,
                                    xTh);

  // 2) fused qk projection: i8 16x16x64, 3-MFMA, bias+quant epilogue
  gemm_proj_i8<<<dim3(2048 / 128, N / 128), 256, 0, stream>>>(
      xq_hi, xq_lo, Wqk_hi, Wqk_lo, bq, bk, qk_hi, qk_lo);

  // 3) S = q k^T + tile softmax stats -> E fp16, stats (m_t, l_t)
  gemm_s_stats<<<dim3(N / 128, N / 128), 256, 0, stream>>>(
      qk_hi, qk_lo, qk_hi + 1024, qk_lo + 1024, E, stats);

  // 4) out = sum_t beta_t (E_t x): beta prologue + in-block split-K=2
  gemm_av<<<256, 512, 0, stream>>>((const uint16_t*)E, xTh, stats, out);

  (void)in_sizes; (void)n_in; (void)out_size; (void)ws_size;
}

// Round 3
// 218.167 us; speedup vs baseline: 1.1175x; 1.0035x over previous
//
#include <hip/hip_runtime.h>
#include <hip/hip_bf16.h>
#include <hip/hip_fp16.h>
#include <stdint.h>

// ---------------------------------------------------------------------------
// CLIPAttentionPooling. R12: epilogue store-issue attack.
// R11 post-mortem: s_stats pipes sum to ~100% busy with no overlap; the
// unmodeled 4th pipe is VMEM store issue: 64 scalar 2B stores/thread (E),
// 128 scalar 1B stores/thread (proj), 64 scalar 4B stores/thread (av)
// ~= 65K store insts/CU ~= 40% of kernel. Fix: LDS-transpose epilogues --
// write C-fragments to a chunk-XOR-swizzled LDS image, barrier, read back
// b128-coalesced, store 16B/lane. Bytes moved are verbatim (absmax equal).
//   * s_stats: 64 short-stores -> 8 dwordx4.
//   * proj: pack hi|lo<<8 u16 image -> byte-unpack -> 16 dwordx2 (was 128 b).
//   * av: fp32 image; ALL 512 threads store (z=1 was idle) -> 8 dwordx4.
// K-loop structure unchanged from R11 (single-barrier 2-phase, 32-bit offs).
// ---------------------------------------------------------------------------

using half8   = __attribute__((ext_vector_type(8))) _Float16;
using float4v = __attribute__((ext_vector_type(4))) float;
using int4v   = __attribute__((ext_vector_type(4))) int;
using uint2v  = __attribute__((ext_vector_type(2))) unsigned int;

// q/k int16 grid: covers +-6.0, v = QS*(256*hi+lo)
#define QS        (6.0f / 32768.0f)
#define INV_S     (32768.0f / 6.0f)
#define INV_S256  (128.0f / 6.0f)
#define C_HH      (65536.0f * QS * QS)
#define C_X       (256.0f * QS * QS)

// x grid: +-6.0 ; W grid: +-0.25
#define SX        (6.0f / 32768.0f)
#define SW        (0.25f / 32768.0f)
#define P_HH      (65536.0f * SX * SW)
#define P_X       (256.0f * SX * SW)

#define GLOAD_LDS16(gptr, ldsptr)                                              \
  __builtin_amdgcn_global_load_lds(                                            \
      (__attribute__((address_space(1))) void*)(uintptr_t)(gptr),              \
      (__attribute__((address_space(3))) void*)(unsigned)(uintptr_t)(ldsptr),  \
      16, 0, 0)

__device__ __forceinline__ void barrier_raw() {
  asm volatile("" ::: "memory");
  __builtin_amdgcn_s_barrier();
  asm volatile("" ::: "memory");
}

// chunk-level swizzle for the epilogue images: spreads the 4 quads and 4 r's
// of a C-fragment write across banks (2 words/bank = the wave64 minimum).
__device__ __forceinline__ int swz3(int row) {
  return (((row >> 2) & 3) << 1) ^ (row & 3);
}

// ---------------------------------------------------------------------------
// S GEMM + tile softmax stats. Split-i8 16x16x64, 128x128 tile, BK=64.
// R12: LDS-image epilogue for E stores.
__global__ __launch_bounds__(256, 2) void gemm_s_stats(
    const int8_t* __restrict__ Ahi, const int8_t* __restrict__ Alo,
    const int8_t* __restrict__ Bhi, const int8_t* __restrict__ Blo,
    _Float16* __restrict__ E, float2* __restrict__ stats)
{
  __shared__ __align__(16) int8_t smem[65536];
  int8_t* sAh = smem;            // [2][8192]
  int8_t* sAl = smem + 16384;    // [2][8192]
  int8_t* sBh = smem + 32768;    // [2][8192]
  int8_t* sBl = smem + 49152;    // [2][8192]

  const int tid  = threadIdx.x;
  const int wave = tid >> 6;
  const int lane = tid & 63;
  const int quad = lane >> 4;
  const int t16  = lane & 15;
  const int wm   = wave & 1;
  const int wn   = wave >> 1;
  const int row0 = blockIdx.y * 128;
  const int col0 = blockIdx.x * 128;

  const int seg  = lane & 3;   // 16B chunk within 64B row
  const int rsub = lane >> 2;  // row within 16-row stripe

  const int offA0 = (row0 + wave * 16 + rsub) * 2048 + seg * 16;
  const int offA1 = offA0 + 64 * 2048;
  const int offB0 = (col0 + wave * 16 + rsub) * 2048 + seg * 16;
  const int offB1 = offB0 + 64 * 2048;
  const int ldsT0 = (wave * 16) * 64;
  const int ldsT1 = (64 + wave * 16) * 64;

  int4v hh[4][4], cc[4][4];
#pragma unroll
  for (int i = 0; i < 4; ++i)
#pragma unroll
    for (int j = 0; j < 4; ++j) {
      hh[i][j] = (int4v){0, 0, 0, 0};
      cc[i][j] = (int4v){0, 0, 0, 0};
    }

  auto stage_k = [&](int ks, int b) {
    const int k0 = ks * 64;
    GLOAD_LDS16(Ahi + offA0 + k0, sAh + b * 8192 + ldsT0);
    GLOAD_LDS16(Ahi + offA1 + k0, sAh + b * 8192 + ldsT1);
    GLOAD_LDS16(Alo + offA0 + k0, sAl + b * 8192 + ldsT0);
    GLOAD_LDS16(Alo + offA1 + k0, sAl + b * 8192 + ldsT1);
    GLOAD_LDS16(Bhi + offB0 + k0, sBh + b * 8192 + ldsT0);
    GLOAD_LDS16(Bhi + offB1 + k0, sBh + b * 8192 + ldsT1);
    GLOAD_LDS16(Blo + offB0 + k0, sBl + b * 8192 + ldsT0);
    GLOAD_LDS16(Blo + offB1 + k0, sBl + b * 8192 + ldsT1);
  };

  stage_k(0, 0);
  asm volatile("s_waitcnt vmcnt(0)" ::: "memory");
  barrier_raw();

  int buf = 0;
  for (int ks = 0; ks < 16; ++ks) {
    if (ks < 15) stage_k(ks + 1, buf ^ 1);

    int4v ah[4], al[4], bh[4], bl[4];
#pragma unroll
    for (int i = 0; i < 4; ++i) {
      const int ao = buf * 8192 + (wm * 64 + i * 16 + t16) * 64 + quad * 16;
      ah[i] = *(const int4v*)(sAh + ao);
      al[i] = *(const int4v*)(sAl + ao);
    }
#pragma unroll
    for (int j = 0; j < 4; ++j) {
      const int bo = buf * 8192 + (wn * 64 + j * 16 + t16) * 64 + quad * 16;
      bh[j] = *(const int4v*)(sBh + bo);
      bl[j] = *(const int4v*)(sBl + bo);
    }

    __builtin_amdgcn_s_setprio(1);
#pragma unroll
    for (int i = 0; i < 4; ++i)
#pragma unroll
      for (int j = 0; j < 4; ++j) {
        hh[i][j] = __builtin_amdgcn_mfma_i32_16x16x64_i8(ah[i], bh[j], hh[i][j], 0, 0, 0);
        cc[i][j] = __builtin_amdgcn_mfma_i32_16x16x64_i8(ah[i], bl[j], cc[i][j], 0, 0, 0);
        cc[i][j] = __builtin_amdgcn_mfma_i32_16x16x64_i8(al[i], bh[j], cc[i][j], 0, 0, 0);
      }
    __builtin_amdgcn_s_setprio(0);

    if (ks < 15) asm volatile("s_waitcnt vmcnt(0)" ::: "memory");
    barrier_raw();
    buf ^= 1;
  }

  // ---- epilogue: tile-local softmax stats + LDS-image E store -------------
  float* red = (float*)smem;  // 1.5 KB at front (dead staging data)

  float vv[4][4][4];
  float rmax[4][4];
#pragma unroll
  for (int i = 0; i < 4; ++i)
#pragma unroll
    for (int r = 0; r < 4; ++r) {
      float mx = -3.0e38f;
#pragma unroll
      for (int j = 0; j < 4; ++j) {
        float v = C_HH * (float)hh[i][j][r] + C_X * (float)cc[i][j][r];
        vv[i][j][r] = v;
        mx = fmaxf(mx, v);
      }
      mx = fmaxf(mx, __shfl_xor(mx, 1));
      mx = fmaxf(mx, __shfl_xor(mx, 2));
      mx = fmaxf(mx, __shfl_xor(mx, 4));
      mx = fmaxf(mx, __shfl_xor(mx, 8));
      rmax[i][r] = mx;
    }
  if (t16 == 0) {
#pragma unroll
    for (int i = 0; i < 4; ++i)
#pragma unroll
      for (int r = 0; r < 4; ++r)
        red[wn * 128 + wm * 64 + i * 16 + quad * 4 + r] = rmax[i][r];
  }
  __syncthreads();

  float mrow[4][4];
#pragma unroll
  for (int i = 0; i < 4; ++i)
#pragma unroll
    for (int r = 0; r < 4; ++r) {
      const int row = wm * 64 + i * 16 + quad * 4 + r;
      mrow[i][r] = fmaxf(red[row], red[128 + row]);
    }

  float rsum[4][4];
#pragma unroll
  for (int i = 0; i < 4; ++i)
#pragma unroll
    for (int r = 0; r < 4; ++r) {
      float s = 0.f;
#pragma unroll
      for (int j = 0; j < 4; ++j) {
        float e = __expf(vv[i][j][r] - mrow[i][r]);
        vv[i][j][r] = e;
        s += e;
      }
      s += __shfl_xor(s, 1);
      s += __shfl_xor(s, 2);
      s += __shfl_xor(s, 4);
      s += __shfl_xor(s, 8);
      rsum[i][r] = s;
    }
  if (t16 == 0) {
#pragma unroll
    for (int i = 0; i < 4; ++i)
#pragma unroll
      for (int r = 0; r < 4; ++r)
        red[256 + wn * 128 + wm * 64 + i * 16 + quad * 4 + r] = rsum[i][r];
  }

  // E fragments -> swizzled u16 image (overlays sBh/sBl: dead after K loop)
  uint16_t* img = (uint16_t*)(smem + 32768);  // [128][128] u16 = 32 KB
#pragma unroll
  for (int i = 0; i < 4; ++i)
#pragma unroll
    for (int j = 0; j < 4; ++j)
#pragma unroll
      for (int r = 0; r < 4; ++r) {
        const int row  = wm * 64 + i * 16 + quad * 4 + r;
        const int col  = wn * 64 + j * 16 + t16;
        const int colS = col ^ (((quad << 1) ^ r) << 3);
        _Float16 h = (_Float16)vv[i][j][r];
        img[row * 128 + colS] = *(const uint16_t*)&h;
      }
  __syncthreads();  // covers red-sum writes AND img writes

  // coalesced E store: 8 x b128 per thread
#pragma unroll
  for (int it = 0; it < 8; ++it) {
    const int row    = wave * 32 + it * 4 + quad;
    const int chunkS = t16 ^ swz3(row);
    int4v v = *(const int4v*)&img[row * 128 + chunkS * 8];
    *(int4v*)&E[(size_t)(row0 + row) * 4096 + col0 + t16 * 8] = v;
  }

  if (wn == 0 && t16 == 0) {
#pragma unroll
    for (int i = 0; i < 4; ++i)
#pragma unroll
      for (int r = 0; r < 4; ++r) {
        const int row = wm * 64 + i * 16 + quad * 4 + r;
        const float l = red[256 + row] + red[256 + 128 + row];
        stats[(size_t)(row0 + row) * 32 + blockIdx.x] =
            make_float2(mrow[i][r], l);
      }
  }
}

// ---------------------------------------------------------------------------
// proj: qk = x Wqk^T + bias, split-i8 3-MFMA, bias + int16-grid quant.
// R12: hi|lo packed u16 LDS image epilogue -> 16 dwordx2 stores (was 128 b).
__global__ __launch_bounds__(256, 2) void gemm_proj_i8(
    const int8_t* __restrict__ Ahi, const int8_t* __restrict__ Alo,
    const int8_t* __restrict__ Bhi, const int8_t* __restrict__ Blo,
    const float* __restrict__ biasQ, const float* __restrict__ biasK,
    int8_t* __restrict__ Ch, int8_t* __restrict__ Cl)
{
  __shared__ __align__(16) int8_t smem[65536];
  int8_t* sAh = smem;
  int8_t* sAl = smem + 16384;
  int8_t* sBh = smem + 32768;
  int8_t* sBl = smem + 49152;

  const int tid  = threadIdx.x;
  const int wave = tid >> 6;
  const int lane = tid & 63;
  const int quad = lane >> 4;
  const int t16  = lane & 15;
  const int wm   = wave & 1;
  const int wn   = wave >> 1;
  const int row0 = blockIdx.y * 128;
  const int col0 = blockIdx.x * 128;

  const int seg  = lane & 3;
  const int rsub = lane >> 2;

  const int offA0 = (row0 + wave * 16 + rsub) * 1024 + seg * 16;
  const int offA1 = offA0 + 64 * 1024;
  const int offB0 = (col0 + wave * 16 + rsub) * 1024 + seg * 16;
  const int offB1 = offB0 + 64 * 1024;
  const int ldsT0 = (wave * 16) * 64;
  const int ldsT1 = (64 + wave * 16) * 64;

  int4v hh[4][4], cc[4][4];
#pragma unroll
  for (int i = 0; i < 4; ++i)
#pragma unroll
    for (int j = 0; j < 4; ++j) {
      hh[i][j] = (int4v){0, 0, 0, 0};
      cc[i][j] = (int4v){0, 0, 0, 0};
    }

  auto stage_k = [&](int ks, int b) {
    const int k0 = ks * 64;
    GLOAD_LDS16(Ahi + offA0 + k0, sAh + b * 8192 + ldsT0);
    GLOAD_LDS16(Ahi + offA1 + k0, sAh + b * 8192 + ldsT1);
    GLOAD_LDS16(Alo + offA0 + k0, sAl + b * 8192 + ldsT0);
    GLOAD_LDS16(Alo + offA1 + k0, sAl + b * 8192 + ldsT1);
    GLOAD_LDS16(Bhi + offB0 + k0, sBh + b * 8192 + ldsT0);
    GLOAD_LDS16(Bhi + offB1 + k0, sBh + b * 8192 + ldsT1);
    GLOAD_LDS16(Blo + offB0 + k0, sBl + b * 8192 + ldsT0);
    GLOAD_LDS16(Blo + offB1 + k0, sBl + b * 8192 + ldsT1);
  };

  stage_k(0, 0);
  asm volatile("s_waitcnt vmcnt(0)" ::: "memory");
  barrier_raw();

  int buf = 0;
  for (int ks = 0; ks < 16; ++ks) {
    if (ks < 15) stage_k(ks + 1, buf ^ 1);

    int4v ah[4], al[4], bh[4], bl[4];
#pragma unroll
    for (int i = 0; i < 4; ++i) {
      const int ao = buf * 8192 + (wm * 64 + i * 16 + t16) * 64 + quad * 16;
      ah[i] = *(const int4v*)(sAh + ao);
      al[i] = *(const int4v*)(sAl + ao);
    }
#pragma unroll
    for (int j = 0; j < 4; ++j) {
      const int bo = buf * 8192 + (wn * 64 + j * 16 + t16) * 64 + quad * 16;
      bh[j] = *(const int4v*)(sBh + bo);
      bl[j] = *(const int4v*)(sBl + bo);
    }

    __builtin_amdgcn_s_setprio(1);
#pragma unroll
    for (int i = 0; i < 4; ++i)
#pragma unroll
      for (int j = 0; j < 4; ++j) {
        hh[i][j] = __builtin_amdgcn_mfma_i32_16x16x64_i8(ah[i], bh[j], hh[i][j], 0, 0, 0);
        cc[i][j] = __builtin_amdgcn_mfma_i32_16x16x64_i8(ah[i], bl[j], cc[i][j], 0, 0, 0);
        cc[i][j] = __builtin_amdgcn_mfma_i32_16x16x64_i8(al[i], bh[j], cc[i][j], 0, 0, 0);
      }
    __builtin_amdgcn_s_setprio(0);

    if (ks < 15) asm volatile("s_waitcnt vmcnt(0)" ::: "memory");
    barrier_raw();
    buf ^= 1;
  }

  // ---- epilogue: quant -> packed u16 image -> coalesced plane stores ------
  uint16_t* img = (uint16_t*)(smem + 32768);  // [128][128] u16
#pragma unroll
  for (int i = 0; i < 4; ++i) {
#pragma unroll
    for (int j = 0; j < 4; ++j) {
      const int ccol = col0 + wn * 64 + j * 16 + t16;
      const float* bp = (ccol < 1024) ? biasQ : (biasK - 1024);
#pragma unroll
      for (int r = 0; r < 4; ++r) {
        float v = P_HH * (float)hh[i][j][r] + P_X * (float)cc[i][j][r] + bp[ccol];
        int hi = (int)lrintf(v * INV_S256);
        hi = hi > 127 ? 127 : (hi < -127 ? -127 : hi);
        int lo = (int)lrintf(v * INV_S - 256.0f * (float)hi);
        lo = lo > 127 ? 127 : (lo < -127 ? -127 : lo);
        const int row  = wm * 64 + i * 16 + quad * 4 + r;
        const int col  = wn * 64 + j * 16 + t16;
        const int colS = col ^ (((quad << 1) ^ r) << 3);
        img[row * 128 + colS] = (uint16_t)((hi & 0xff) | ((lo & 0xff) << 8));
      }
    }
  }
  __syncthreads();

#pragma unroll
  for (int it = 0; it < 8; ++it) {
    const int row    = wave * 32 + it * 4 + quad;
    const int chunkS = t16 ^ swz3(row);
    int4v p = *(const int4v*)&img[row * 128 + chunkS * 8];
    const unsigned w0 = (unsigned)p[0], w1 = (unsigned)p[1];
    const unsigned w2 = (unsigned)p[2], w3 = (unsigned)p[3];
    uint2v hw, lw;
    hw[0] = (w0 & 0xffu) | (((w0 >> 16) & 0xffu) << 8) |
            ((w1 & 0xffu) << 16) | (((w1 >> 16) & 0xffu) << 24);
    hw[1] = (w2 & 0xffu) | (((w2 >> 16) & 0xffu) << 8) |
            ((w3 & 0xffu) << 16) | (((w3 >> 16) & 0xffu) << 24);
    lw[0] = ((w0 >> 8) & 0xffu) | (((w0 >> 24) & 0xffu) << 8) |
            (((w1 >> 8) & 0xffu) << 16) | ((w1 >> 24) << 24);
    lw[1] = ((w2 >> 8) & 0xffu) | (((w2 >> 24) & 0xffu) << 8) |
            (((w3 >> 8) & 0xffu) << 16) | ((w3 >> 24) << 24);
    const size_t go = (size_t)(row0 + row) * 2048 + col0 + t16 * 8;
    *(uint2v*)&Ch[go] = hw;
    *(uint2v*)&Cl[go] = lw;
  }
}

// ---------------------------------------------------------------------------
// AV: out = sum_t beta_t (E_t x). 512 threads, in-block split-K=2.
// R12: fp32 LDS-image store epilogue; all 512 threads store (8 dwordx4 each).
__global__ __launch_bounds__(512) void gemm_av(
    const uint16_t* __restrict__ E, const uint16_t* __restrict__ B,
    const float2* __restrict__ stats, float* __restrict__ out)
{
  // [buf][z][ A:128x64h | B:128x64h ] = 128 KB
  __shared__ __align__(16) uint16_t stg[2][2][16384];
  __shared__ float betaS[128 * 33];

  const int L      = blockIdx.x;        // 0..255
  const int xcd    = L & 7;
  const int rest   = L >> 3;            // 0..31
  const int colb   = rest & 7;          // 0..7
  const int bandHi = rest >> 3;         // 0..3
  const int band   = xcd + 8 * bandHi;  // 0..31
  const int row0   = band * 128;
  const int col0   = colb * 128;

  const int tid  = threadIdx.x;
  const int wave = tid >> 6;
  const int z    = wave >> 2;           // wave-group = K-half
  const int gw   = wave & 3;            // group-local wave
  const int lane = tid & 63;
  const int quad = lane >> 4;
  const int t16  = lane & 15;
  const int wm   = gw & 1;
  const int wn   = gw >> 1;

  const int c8   = lane & 7;            // 16B-chunk within 128B row
  const int r8   = lane >> 3;           // row within 8-row stripe
  const int srcC = (c8 - r8) & 7;       // rotate: LDS[row][c] = glob[(c-row)&7]

  int offA[4], offB[4];
#pragma unroll
  for (int r = 0; r < 4; ++r) {
    offA[r] = (row0 + r * 32 + gw * 8 + r8) * 4096 + srcC * 8;
    offB[r] = (col0 + r * 32 + gw * 8 + r8) * 4096 + srcC * 8;
  }

  auto stage_s = [&](int s, int b) {
    const int k0h = (z * 16 + (s >> 1)) * 128 + (s & 1) * 64;
    uint16_t* sA = &stg[b][z][0];
    uint16_t* sB = &stg[b][z][8192];
#pragma unroll
    for (int r = 0; r < 4; ++r) {
      GLOAD_LDS16(E + offA[r] + k0h, &sA[(r * 32 + gw * 8) * 64]);
      GLOAD_LDS16(B + offB[r] + k0h, &sB[(r * 32 + gw * 8) * 64]);
    }
  };

  stage_s(0, 0);  // latency hides under the beta prologue

  if (tid < 128) {
    const int row = row0 + tid;
    float2 st[32];
    float m = -3.0e38f;
#pragma unroll
    for (int t = 0; t < 32; ++t) {
      st[t] = stats[(size_t)row * 32 + t];
      m = fmaxf(m, st[t].x);
    }
    float l = 0.f;
#pragma unroll
    for (int t = 0; t < 32; ++t) l += st[t].y * __expf(st[t].x - m);
    const float inv = 1.0f / l;
#pragma unroll
    for (int t = 0; t < 32; ++t)
      betaS[tid * 33 + t] = __expf(st[t].x - m) * inv;
  }
  asm volatile("s_waitcnt vmcnt(0)" ::: "memory");
  __syncthreads();

  float4v acc[4][4];
#pragma unroll
  for (int i = 0; i < 4; ++i)
#pragma unroll
    for (int j = 0; j < 4; ++j)
      acc[i][j] = (float4v){0.f, 0.f, 0.f, 0.f};

  int buf = 0;
  for (int s = 0; s < 32; ++s) {
    if (s < 31) stage_s(s + 1, buf ^ 1);

    const int t = z * 16 + (s >> 1);
    _Float16 bb[4];
#pragma unroll
    for (int i = 0; i < 4; ++i)
      bb[i] = (_Float16)betaS[(wm * 64 + i * 16 + t16) * 33 + t];

    const uint16_t* sA = &stg[buf][z][0];
    const uint16_t* sB = &stg[buf][z][8192];

    half8 af[2][4], bf[2][4];
#pragma unroll
    for (int ks = 0; ks < 2; ++ks) {
#pragma unroll
      for (int i = 0; i < 4; ++i) {
        const int row = wm * 64 + i * 16 + t16;
        const int ch  = (ks * 4 + quad + (t16 & 7)) & 7;
        af[ks][i] = *(const half8*)&sA[row * 64 + ch * 8];
        half8 bs;
#pragma unroll
        for (int c = 0; c < 8; ++c) bs[c] = bb[i];
        af[ks][i] = af[ks][i] * bs;
      }
#pragma unroll
      for (int j = 0; j < 4; ++j) {
        const int row = wn * 64 + j * 16 + t16;
        const int ch  = (ks * 4 + quad + (t16 & 7)) & 7;
        bf[ks][j] = *(const half8*)&sB[row * 64 + ch * 8];
      }
    }

    __builtin_amdgcn_s_setprio(1);
#pragma unroll
    for (int ks = 0; ks < 2; ++ks)
#pragma unroll
      for (int i = 0; i < 4; ++i)
#pragma unroll
        for (int j = 0; j < 4; ++j)
          acc[i][j] = __builtin_amdgcn_mfma_f32_16x16x32_f16(af[ks][i], bf[ks][j], acc[i][j], 0, 0, 0);
    __builtin_amdgcn_s_setprio(0);

    if (s < 31) asm volatile("s_waitcnt vmcnt(0)" ::: "memory");
    barrier_raw();
    buf ^= 1;
  }

  // ---- combine group1 -> group0 via LDS (two 32 KB halves) ----------------
  float* xfer = (float*)stg;  // bytes [0, 32K)
#pragma unroll
  for (int h = 0; h < 2; ++h) {
    if (z == 1) {
#pragma unroll
      for (int i = 2 * h; i < 2 * h + 2; ++i)
#pragma unroll
        for (int j = 0; j < 4; ++j)
#pragma unroll
          for (int r = 0; r < 4; ++r) {
            const int e = (i - 2 * h) * 16 + j * 4 + r;
            xfer[e * 256 + gw * 64 + lane] = acc[i][j][r];
          }
    }
    __syncthreads();
    if (z == 0) {
#pragma unroll
      for (int i = 2 * h; i < 2 * h + 2; ++i)
#pragma unroll
        for (int j = 0; j < 4; ++j)
#pragma unroll
          for (int r = 0; r < 4; ++r) {
            const int e = (i - 2 * h) * 16 + j * 4 + r;
            acc[i][j][r] += xfer[e * 256 + gw * 64 + lane];
          }
    }
    __syncthreads();
  }

  // ---- fp32 image store: z=0 writes image, ALL 512 threads store ----------
  float* img = (float*)((int8_t*)stg + 65536);  // [128][128] f32 = 64 KB
  if (z == 0) {
#pragma unroll
    for (int i = 0; i < 4; ++i)
#pragma unroll
      for (int j = 0; j < 4; ++j)
#pragma unroll
        for (int r = 0; r < 4; ++r) {
          const int row  = wm * 64 + i * 16 + quad * 4 + r;
          const int col  = wn * 64 + j * 16 + t16;
          const int colS = col ^ (((quad << 1) ^ r) << 2);
          img[row * 128 + colS] = acc[i][j][r];
        }
  }
  __syncthreads();

#pragma unroll
  for (int it = 0; it < 8; ++it) {
    const int row    = wave * 16 + (lane >> 2);
    const int chunk  = (lane & 3) * 8 + it;          // 32 chunks of 4 floats
    const int chunkS = chunk ^ swz3(row);
    float4v v = *(const float4v*)&img[row * 128 + chunkS * 4];
    *(float4v*)&out[(size_t)(row0 + row) * 1024 + col0 + chunk * 4] = v;
  }
}

// ---------------------------------------------------------------------------
// Fused quant + transpose-cast (unchanged).
__global__ __launch_bounds__(256) void quantT(
    const float* __restrict__ x, const float* __restrict__ Wq,
    const float* __restrict__ Wk,
    int8_t* __restrict__ xhi, int8_t* __restrict__ xlo,
    int8_t* __restrict__ whi, int8_t* __restrict__ wlo,
    uint16_t* __restrict__ xT)
{
  if (blockIdx.x < 6144) {
    int i = blockIdx.x * 256 + threadIdx.x;  // 0..1572863
    const float* src; int8_t* dh; int8_t* dl; int idx; float s256, s;
    if (i < 1048576)      { src = x;  idx = i;           dh = xhi; dl = xlo;
                            s256 = INV_S256; s = INV_S; }
    else if (i < 1310720) { src = Wq; idx = i - 1048576; dh = whi; dl = wlo;
                            s256 = 512.0f; s = 131072.0f; }
    else                  { src = Wk; idx = i - 1310720; dh = whi + 1048576;
                            dl = wlo + 1048576; s256 = 512.0f; s = 131072.0f; }
    float4 v = ((const float4*)src)[idx];
    float vv[4] = {v.x, v.y, v.z, v.w};
    int hp = 0, lp = 0;
#pragma unroll
    for (int c = 0; c < 4; ++c) {
      int h = (int)lrintf(vv[c] * s256);
      h = h > 127 ? 127 : (h < -127 ? -127 : h);
      int l = (int)lrintf(vv[c] * s - 256.0f * (float)h);
      l = l > 127 ? 127 : (l < -127 ? -127 : l);
      hp |= (h & 0xff) << (8 * c);
      lp |= (l & 0xff) << (8 * c);
    }
    ((int*)dh)[idx] = hp;
    ((int*)dl)[idx] = lp;
  } else {
    __shared__ float tile[32][33];
    const int tb = blockIdx.x - 6144;   // 0..4095
    const int bx = tb & 31;             // D/32
    const int by = tb >> 5;             // N/32
    const int tx = threadIdx.x & 31;
    const int ty = threadIdx.x >> 5;    // 0..7
#pragma unroll
    for (int p = 0; p < 4; ++p) {
      const int row = by * 32 + ty + p * 8;
      tile[ty + p * 8][tx] = x[(size_t)row * 1024 + bx * 32 + tx];
    }
    __syncthreads();
#pragma unroll
    for (int p = 0; p < 4; ++p) {
      const int oc = ty + p * 8;  // local col in x == local row in xT
      __half hv = __float2half_rn(tile[tx][oc]);
      xT[(size_t)(bx * 32 + oc) * 4096 + by * 32 + tx] = *(uint16_t*)&hv;
    }
  }
}

extern "C" void kernel_launch(void* const* d_in, const int* in_sizes, int n_in,
                              void* d_out, int out_size, void* d_ws, size_t ws_size,
                              hipStream_t stream) {
  const int N = 4096, D = 1024;
  const float* x  = (const float*)d_in[0];
  const float* Wq = (const float*)d_in[1];
  const float* bq = (const float*)d_in[2];
  const float* Wk = (const float*)d_in[3];
  const float* bk = (const float*)d_in[4];
  float* out = (float*)d_out;

  // workspace layout (MiB offsets)
  char* w = (char*)d_ws;
  const size_t MiB = 1024 * 1024;
  int8_t*    xq_hi  = (int8_t*)   (w + 0  * MiB);  // [N x D]
  int8_t*    xq_lo  = (int8_t*)   (w + 4  * MiB);
  int8_t*    Wqk_hi = (int8_t*)   (w + 8  * MiB);  // [2048 x D]
  int8_t*    Wqk_lo = (int8_t*)   (w + 10 * MiB);
  int8_t*    qk_hi  = (int8_t*)   (w + 12 * MiB);  // [N x 2048]
  int8_t*    qk_lo  = (int8_t*)   (w + 20 * MiB);
  _Float16*  E      = (_Float16*) (w + 36 * MiB);  // [N x N] fp16, 32 MiB
  float2*    stats  = (float2*)   (w + 68 * MiB);  // [N x 32] (m,l), 1 MiB
  uint16_t*  xTh    = (uint16_t*) (w + 72 * MiB);  // [D x N] fp16
  // total 80 MiB

  // 1) fused quantization + transpose-cast  (6144 + 4096 blocks)
  quantT<<<10240, 256, 0, stream>>>(x, Wq, Wk, xq_hi, xq_lo, Wqk_hi, Wqk_lo,
                                    xTh);

  // 2) fused qk projection: i8 16x16x64, 3-MFMA, bias+quant epilogue
  gemm_proj_i8<<<dim3(2048 / 128, N / 128), 256, 0, stream>>>(
      xq_hi, xq_lo, Wqk_hi, Wqk_lo, bq, bk, qk_hi, qk_lo);

  // 3) S = q k^T + tile softmax stats -> E fp16, stats (m_t, l_t)
  gemm_s_stats<<<dim3(N / 128, N / 128), 256, 0, stream>>>(
      qk_hi, qk_lo, qk_hi + 1024, qk_lo + 1024, E, stats);

  // 4) out = sum_t beta_t (E_t x): beta prologue + in-block split-K=2
  gemm_av<<<256, 512, 0, stream>>>((const uint16_t*)E, xTh, stats, out);

  (void)in_sizes; (void)n_in; (void)out_size; (void)ws_size;
}